// Round 5
// baseline (84.615 us; speedup 1.0000x reference)
//
#include <hip/hip_runtime.h>

#define TT 4096
#define LOG2PI 1.8378770664093453

// ws layout: 64 slots, stride 96 floats (384 B):
//   slot[b][0..63]  = per-sensor z partial (sum over block's 64 timesteps)
//   slot[b][64..67] = per-group Sq partial (sum of raw y^2)
//   slot[b][68..71] = per-group sy2 partial (sum of ybar^2)
//   slot[b][72..83] = element (b0,b1,h0..h5,g, pad x3), 16B-aligned
//   slot[b][95]     = ready flag (sentinel 1.0f; ws poisoned 0xAA each call)

#define FLAG_OFF 95
#define SENTINEL 1.0f

struct MRed {
    float a00, a01, a10, a11;        // A2
    float b0a, b0b, b1a, b1b;        // B
    float c0, cx, c1;                // C sym
    float j00, j01, j11;             // J top 2x2
    float ja, jb, jc, jd;            // J cross
    float p4d, p4o, p4x, p4e, p4f;   // J4 block
};

struct DRed {
    float g00, g01, g10, g11;        // G2 = inv(I + C*J2)
    float ga00, ga01, ga10, ga11;    // G2*A2
    float d0a, d0b, d1a, d1b;        // delta
    float gc00, gc01, gc10, gc11;    // G2*C
    float clev;
};

struct Elem { float b0, b1, h0, h1, h2, h3, h4, h5, g; };

__device__ __forceinline__ DRed derive(const MRed& M, bool want_clev) {
    DRed D;
    const float cj00 = M.c0 * M.j00 + M.cx * M.j01;
    const float cj01 = M.c0 * M.j01 + M.cx * M.j11;
    const float cj10 = M.cx * M.j00 + M.c1 * M.j01;
    const float cj11 = M.cx * M.j01 + M.c1 * M.j11;
    const float m00 = 1.f + cj00, m01 = cj01, m10 = cj10, m11 = 1.f + cj11;
    const float det = m00 * m11 - m01 * m10;
    const float id = 1.f / det;
    D.g00 = m11 * id; D.g01 = -m01 * id; D.g10 = -m10 * id; D.g11 = m00 * id;
    D.clev = want_clev ? (-0.5f * logf(det)) : 0.f;
    const float CJa0 = M.c0 * M.ja + M.cx * M.jc, CJa1 = M.cx * M.ja + M.c1 * M.jc;
    const float CJb0 = M.c0 * M.jb + M.cx * M.jd, CJb1 = M.cx * M.jb + M.c1 * M.jd;
    const float g0a = -(D.g00 * CJa0 + D.g01 * CJa1);
    const float g1a = -(D.g10 * CJa0 + D.g11 * CJa1);
    const float g0b = -(D.g00 * CJb0 + D.g01 * CJb1);
    const float g1b = -(D.g10 * CJb0 + D.g11 * CJb1);
    D.ga00 = D.g00 * M.a00 + D.g01 * M.a10; D.ga01 = D.g00 * M.a01 + D.g01 * M.a11;
    D.ga10 = D.g10 * M.a00 + D.g11 * M.a10; D.ga11 = D.g10 * M.a01 + D.g11 * M.a11;
    D.d0a = D.g00 * M.b0a + D.g01 * M.b1a + g0a;
    D.d1a = D.g10 * M.b0a + D.g11 * M.b1a + g1a;
    D.d0b = D.g00 * M.b0b + D.g01 * M.b1b + g0b;
    D.d1b = D.g10 * M.b0b + D.g11 * M.b1b + g1b;
    D.gc00 = D.g00 * M.c0 + D.g01 * M.cx; D.gc01 = D.g00 * M.cx + D.g01 * M.c1;
    D.gc10 = D.g10 * M.c0 + D.g11 * M.cx; D.gc11 = D.g10 * M.cx + D.g11 * M.c1;
    return D;
}

__device__ __forceinline__ void mupdate(MRed& M, const DRed& D) {
    const float k00 = M.j00 * D.ga00 + M.j01 * D.ga10, k01 = M.j00 * D.ga01 + M.j01 * D.ga11;
    const float k10 = M.j01 * D.ga00 + M.j11 * D.ga10, k11 = M.j01 * D.ga01 + M.j11 * D.ga11;
    const float V0a = M.j00 * D.d0a + M.j01 * D.d1a + M.ja;
    const float V1a = M.j01 * D.d0a + M.j11 * D.d1a + M.jc;
    const float V0b = M.j00 * D.d0b + M.j01 * D.d1b + M.jb;
    const float V1b = M.j01 * D.d0b + M.j11 * D.d1b + M.jd;
    const float U0a = M.a00 * V0a + M.a10 * V1a, U1a = M.a01 * V0a + M.a11 * V1a;
    const float U0b = M.a00 * V0b + M.a10 * V1b, U1b = M.a01 * V0b + M.a11 * V1b;
    const float Ta0 = M.b0a * k00 + M.b1a * k10 + M.ja * D.ga00 + M.jc * D.ga10;
    const float Ta1 = M.b0a * k01 + M.b1a * k11 + M.ja * D.ga01 + M.jc * D.ga11;
    const float Tb0 = M.b0b * k00 + M.b1b * k10 + M.jb * D.ga00 + M.jd * D.ga10;
    const float Tb1 = M.b0b * k01 + M.b1b * k11 + M.jb * D.ga01 + M.jd * D.ga11;
    const float Eaa = M.b0a * V0a + M.b1a * V1a + M.ja * D.d0a + M.jc * D.d1a;
    const float Eab = M.b0a * V0b + M.b1a * V1b + M.ja * D.d0b + M.jc * D.d1b;
    const float Eba = M.b0b * V0a + M.b1b * V1a + M.jb * D.d0a + M.jd * D.d1a;
    const float Ebb = M.b0b * V0b + M.b1b * V1b + M.jb * D.d0b + M.jd * D.d1b;
    const float nj00 = M.j00 + (M.a00 * k00 + M.a10 * k10);
    const float nj11 = M.j11 + (M.a01 * k01 + M.a11 * k11);
    const float nj01 = M.j01 + 0.5f * ((M.a00 * k01 + M.a10 * k11) + (M.a01 * k00 + M.a11 * k10));
    const float nja = M.ja + 0.5f * (U0a + Ta0);
    const float njc = M.jc + 0.5f * (U1a + Ta1);
    const float njb = M.jb + 0.5f * (U0b + Tb0);
    const float njd = M.jd + 0.5f * (U1b + Tb1);
    const float np4d = M.p4d + Eaa, np4o = M.p4o + Eaa;
    const float np4x = M.p4x + 0.5f * (Eab + Eba);
    const float np4e = M.p4e + Ebb, np4f = M.p4f + Ebb;
    const float ta = M.a00 * D.gc00 + M.a01 * D.gc10, tb = M.a00 * D.gc01 + M.a01 * D.gc11;
    const float tc = M.a10 * D.gc00 + M.a11 * D.gc10, td = M.a10 * D.gc01 + M.a11 * D.gc11;
    const float X00 = ta * M.a00 + tb * M.a01, X01 = ta * M.a10 + tb * M.a11;
    const float X10 = tc * M.a00 + td * M.a01, X11 = tc * M.a10 + td * M.a11;
    const float nc0 = M.c0 + X00, ncx = M.cx + 0.5f * (X01 + X10), nc1 = M.c1 + X11;
    const float na00 = M.a00 * D.ga00 + M.a01 * D.ga10, na01 = M.a00 * D.ga01 + M.a01 * D.ga11;
    const float na10 = M.a10 * D.ga00 + M.a11 * D.ga10, na11 = M.a10 * D.ga01 + M.a11 * D.ga11;
    const float nb0a = M.a00 * D.d0a + M.a01 * D.d1a + M.b0a;
    const float nb1a = M.a10 * D.d0a + M.a11 * D.d1a + M.b1a;
    const float nb0b = M.a00 * D.d0b + M.a01 * D.d1b + M.b0b;
    const float nb1b = M.a10 * D.d0b + M.a11 * D.d1b + M.b1b;
    M.a00 = na00; M.a01 = na01; M.a10 = na10; M.a11 = na11;
    M.b0a = nb0a; M.b0b = nb0b; M.b1a = nb1a; M.b1b = nb1b;
    M.c0 = nc0; M.cx = ncx; M.c1 = nc1;
    M.j00 = nj00; M.j01 = nj01; M.j11 = nj11;
    M.ja = nja; M.jb = njb; M.jc = njc; M.jd = njd;
    M.p4d = np4d; M.p4o = np4o; M.p4x = np4x; M.p4e = np4e; M.p4f = np4f;
}

__device__ __forceinline__ Elem shfl_elem(const Elem& e, int src) {
    Elem r;
    r.b0 = __shfl(e.b0, src, 64); r.b1 = __shfl(e.b1, src, 64);
    r.h0 = __shfl(e.h0, src, 64); r.h1 = __shfl(e.h1, src, 64);
    r.h2 = __shfl(e.h2, src, 64); r.h3 = __shfl(e.h3, src, 64);
    r.h4 = __shfl(e.h4, src, 64); r.h5 = __shfl(e.h5, src, 64);
    r.g  = __shfl(e.g,  src, 64);
    return r;
}

__device__ __forceinline__ Elem compose_red(const MRed& M, const DRed& D,
                                            const Elem& e1, const Elem& e2) {
    const float Jb0 = M.j00 * e1.b0 + M.j01 * e1.b1;
    const float Jb1 = M.j01 * e1.b0 + M.j11 * e1.b1;
    const float Jba = M.ja * e1.b0 + M.jc * e1.b1;
    const float Jbb = M.jb * e1.b0 + M.jd * e1.b1;
    const float Gb0 = D.g00 * e1.b0 + D.g01 * e1.b1;
    const float Gb1 = D.g10 * e1.b0 + D.g11 * e1.b1;
    const float t0 = e1.b0 + M.c0 * e2.h0 + M.cx * e2.h1;
    const float t1 = e1.b1 + M.cx * e2.h0 + M.c1 * e2.h1;
    const float u0 = D.g00 * t0 + D.g01 * t1;
    const float u1 = D.g10 * t0 + D.g11 * t1;
    Elem o;
    o.b0 = M.a00 * u0 + M.a01 * u1 + e2.b0;
    o.b1 = M.a10 * u0 + M.a11 * u1 + e2.b1;
    const float w0 = e2.h0 - Jb0, w1 = e2.h1 - Jb1;
    const float w2 = e2.h2 - Jba, w3 = e2.h3 - Jba;
    const float w4 = e2.h4 - Jbb, w5 = e2.h5 - Jbb;
    o.h0 = e1.h0 + w0 * D.ga00 + w1 * D.ga10;
    o.h1 = e1.h1 + w0 * D.ga01 + w1 * D.ga11;
    o.h2 = e1.h2 + w0 * D.d0a + w1 * D.d1a + w2;
    o.h3 = e1.h3 + w0 * D.d0a + w1 * D.d1a + w3;
    o.h4 = e1.h4 + w0 * D.d0b + w1 * D.d1b + w4;
    o.h5 = e1.h5 + w0 * D.d0b + w1 * D.d1b + w5;
    const float q1 = Jb0 * Gb0 + Jb1 * Gb1;
    const float bil = e2.h0 * Gb0 + e2.h1 * Gb1;
    const float q2 = e2.h0 * (D.gc00 * e2.h0 + D.gc01 * e2.h1)
                   + e2.h1 * (D.gc10 * e2.h0 + D.gc11 * e2.h1);
    o.g = e1.g + e2.g + D.clev - 0.5f * q1 + bil + 0.5f * q2;
    return o;
}

__device__ __forceinline__ MRed m_init(float a0, float a1, float q, float rr,
                                       float& c, float& kpp, float& glc) {
    c = 16.f * q / (rr * (rr + 32.f * q));
    const float s2 = 1.f / rr - 2.f * c;
    kpp = 4.f * q * s2;
    const float om8 = 1.f - 8.f * kpp;
    glc = 2.f * (float)LOG2PI + logf(rr) + logf(rr + 32.f * q);
    MRed M;
    M.a00 = 0.f; M.a01 = om8 * a0; M.a10 = om8 * a1; M.a11 = 0.f;
    M.b0a = -kpp; M.b0b = 0.f; M.b1a = 0.f; M.b1b = -kpp;
    M.c0 = om8 * q; M.cx = 0.f; M.c1 = om8 * q;
    M.j00 = 32.f * a1 * a1 * s2; M.j01 = 0.f; M.j11 = 32.f * a0 * a0 * s2;
    M.ja = 0.f; M.jb = 4.f * a1 * s2; M.jc = 4.f * a0 * s2; M.jd = 0.f;
    const float Sd = 1.f / rr - c, So = -c;
    M.p4d = Sd; M.p4o = So; M.p4x = 0.f; M.p4e = Sd; M.p4f = So;
    return M;
}

__global__ __launch_bounds__(256) void fused_kernel(const float* __restrict__ track,
                                                    float* __restrict__ ws,
                                                    const float* __restrict__ bias_scales,
                                                    const float* __restrict__ obs_noise,
                                                    const float* __restrict__ trans_noise,
                                                    const float* __restrict__ tp,
                                                    float* __restrict__ out) {
    __shared__ float zp[256];
    __shared__ float sqp[16], syp[16];
    __shared__ float4 ybar_s[64];
    const int tid = threadIdx.x, w = tid >> 6, l = tid & 63, b = blockIdx.x;
    const float a0 = tp[0], a1 = tp[1];
    const float q = trans_noise[0] * trans_noise[0];
    const float rr = obs_noise[0] * obs_noise[0];
    const float* base = track + (size_t)b * 64 * 64;
    const int g = ((l >> 5) << 1) | (l & 1);
    const bool writer = (l == 0) || (l == 1) || (l == 32) || (l == 33);
    float accz = 0.f, accsq = 0.f, accy2 = 0.f;
#pragma unroll
    for (int it = 0; it < 16; ++it) {
        const int tl = it * 4 + w;
        const float v = base[tl * 64 + l];
        accz += v; accsq += v * v;
        float s = v;
        s += __shfl_xor(s, 2, 64); s += __shfl_xor(s, 4, 64);
        s += __shfl_xor(s, 8, 64); s += __shfl_xor(s, 16, 64);
        if (writer) {
            const float yb = 0.25f * s;
            ((float*)&ybar_s[tl])[g] = yb;
            accy2 += yb * yb;
        }
    }
    zp[tid] = accz;
    float s2 = accsq;
    s2 += __shfl_xor(s2, 2, 64); s2 += __shfl_xor(s2, 4, 64);
    s2 += __shfl_xor(s2, 8, 64); s2 += __shfl_xor(s2, 16, 64);
    if (writer) { sqp[w * 4 + g] = s2; syp[w * 4 + g] = accy2; }
    __syncthreads();
    if (w != 0) return;                      // waves 1..3 done (LDS handed off)

    float c, kpp, glc;
    MRed M = m_init(a0, a1, q, rr, c, kpp, glc);

    float* slot = ws + b * 96;
    slot[l] = zp[l] + zp[64 + l] + zp[128 + l] + zp[192 + l];
    if (l < 4) {
        slot[64 + l] = sqp[l] + sqp[4 + l] + sqp[8 + l] + sqp[12 + l];
    } else if (l < 8) {
        const int gg = l - 4;
        slot[68 + gg] = syp[gg] + syp[4 + gg] + syp[8 + gg] + syp[12 + gg];
    }

    // leaf build (lane l owns timestep t = 64*b + l)
    const float4 y = ybar_s[l];
    const float irr = 1.f / rr;
    const float bs0 = y.x + y.y, bs1 = y.z + y.w;
    const float v0 = y.x * irr - c * bs0, v1 = y.y * irr - c * bs0;
    const float v2 = y.z * irr - c * bs1, v3 = y.w * irr - c * bs1;
    Elem e;
    e.b0 = kpp * bs0; e.b1 = kpp * bs1;
    e.h0 = 4.f * a1 * (v2 + v3); e.h1 = 4.f * a0 * (v0 + v1);
    e.h2 = v0; e.h3 = v1; e.h4 = v2; e.h5 = v3;
    e.g = -0.5f * (y.x * v0 + y.y * v1 + y.z * v2 + y.w * v3) - glc;

    // local tree: 6 levels, shuffle-only
#pragma unroll
    for (int k = 0; k < 6; ++k) {
        const DRed D = derive(M, true);
        const Elem e1 = shfl_elem(e, (2 * l) & 63);
        const Elem e2 = shfl_elem(e, (2 * l + 1) & 63);
        e = compose_red(M, D, e1, e2);
        mupdate(M, D);
    }
    if (l == 0) {
        float4* eo = (float4*)(slot + 72);
        eo[0] = make_float4(e.b0, e.b1, e.h0, e.h1);
        eo[1] = make_float4(e.h2, e.h3, e.h4, e.h5);
        eo[2] = make_float4(e.g, 0.f, 0.f, 0.f);
    }

    // release: slot data visible device-wide, then set flag
    __threadfence();
    if (l == 0) {
        __atomic_store_n((unsigned*)(slot + FLAG_OFF), __float_as_uint(SENTINEL),
                         __ATOMIC_RELAXED);
    }
    if (b != 0) return;

    // ---- block 0, wave 0: spin until all 64 flags set (all blocks co-resident) ----
    {
        volatile unsigned* fl = (volatile unsigned*)(ws + l * 96 + FLAG_OFF);
        const unsigned want = __float_as_uint(SENTINEL);
        while (true) {
            const bool ready = (*fl == want);
            if (__all(ready)) break;
            __builtin_amdgcn_s_sleep(1);
        }
    }
    __threadfence();   // acquire

    // ---- final stage: wave 0 of block 0 ----
    float zl = 0.f;
#pragma unroll 8
    for (int bb = 0; bb < 64; ++bb) zl += ws[bb * 96 + l];

    const float4* sp = (const float4*)(ws + l * 96 + 64);
    const float4 q0 = sp[0], q1 = sp[1];              // aux: Sq[0..3], sy2[0..3]
    const float4 p0 = sp[2], p1 = sp[3], p2 = sp[4];  // element of block l
    Elem ef;
    ef.b0 = p0.x; ef.b1 = p0.y;
    ef.h0 = p0.z; ef.h1 = p0.w; ef.h2 = p1.x; ef.h3 = p1.y; ef.h4 = p1.z; ef.h5 = p1.w;
    ef.g = p2.x;

    float axv[8] = {q0.x, q0.y, q0.z, q0.w, q1.x, q1.y, q1.z, q1.w};
#pragma unroll
    for (int i = 0; i < 8; ++i) {
        float t = axv[i];
        t += __shfl_xor(t, 1, 64); t += __shfl_xor(t, 2, 64); t += __shfl_xor(t, 4, 64);
        t += __shfl_xor(t, 8, 64); t += __shfl_xor(t, 16, 64); t += __shfl_xor(t, 32, 64);
        axv[i] = t;
    }

    // final 6 tree levels (M already advanced through the 6 local levels)
#pragma unroll
    for (int k = 0; k < 6; ++k) {
        const DRed D = derive(M, true);
        const Elem e1 = shfl_elem(ef, (2 * l) & 63);
        const Elem e2 = shfl_elem(ef, (2 * l + 1) & 63);
        ef = compose_red(M, D, e1, e2);
        mupdate(M, D);
    }

    // group sums of z (per-sensor totals) for the contrast terms
    float sz = zl, sz2 = zl * zl;
    sz += __shfl_xor(sz, 2, 64);  sz2 += __shfl_xor(sz2, 2, 64);
    sz += __shfl_xor(sz, 4, 64);  sz2 += __shfl_xor(sz2, 4, 64);
    sz += __shfl_xor(sz, 8, 64);  sz2 += __shfl_xor(sz2, 8, 64);
    sz += __shfl_xor(sz, 16, 64); sz2 += __shfl_xor(sz2, 16, 64);
    float csz[4], csz2[4];
    csz[0] = __shfl(sz, 0, 64);  csz[1] = __shfl(sz, 1, 64);
    csz[2] = __shfl(sz, 32, 64); csz[3] = __shfl(sz, 33, 64);
    csz2[0] = __shfl(sz2, 0, 64);  csz2[1] = __shfl(sz2, 1, 64);
    csz2[2] = __shfl(sz2, 32, 64); csz2[3] = __shfl(sz2, 33, 64);

    if (l == 0) {
        const float bsc0 = bias_scales[0], bsc1 = bias_scales[1];
        float J6[6][6];
        J6[0][0] = M.j00; J6[0][1] = J6[1][0] = M.j01; J6[1][1] = M.j11;
        J6[0][2] = J6[0][3] = J6[2][0] = J6[3][0] = M.ja;
        J6[0][4] = J6[0][5] = J6[4][0] = J6[5][0] = M.jb;
        J6[1][2] = J6[1][3] = J6[2][1] = J6[3][1] = M.jc;
        J6[1][4] = J6[1][5] = J6[4][1] = J6[5][1] = M.jd;
        J6[2][2] = J6[3][3] = M.p4d; J6[2][3] = J6[3][2] = M.p4o;
        J6[2][4] = J6[2][5] = J6[3][4] = J6[3][5] = M.p4x;
        J6[4][2] = J6[5][2] = J6[4][3] = J6[5][3] = M.p4x;
        J6[4][4] = J6[5][5] = M.p4e; J6[4][5] = J6[5][4] = M.p4f;
        const float s[6] = {1.f, 1.f, sqrtf(bsc0), sqrtf(bsc1), sqrtf(bsc0), sqrtf(bsc1)};
        float Mm[6][6];
#pragma unroll
        for (int i = 0; i < 6; ++i)
#pragma unroll
            for (int j = 0; j < 6; ++j)
                Mm[i][j] = ((i == j) ? 1.f : 0.f) + s[i] * s[j] * J6[i][j];
        float Lo[6][6];
#pragma unroll
        for (int i = 0; i < 6; ++i) {
#pragma unroll
            for (int j = 0; j <= i; ++j) {
                float sum = Mm[i][j];
#pragma unroll
                for (int m = 0; m < 6; ++m) if (m < j) sum -= Lo[i][m] * Lo[j][m];
                if (i == j) Lo[i][i] = sqrtf(sum);
                else Lo[i][j] = sum / Lo[j][j];
            }
        }
        float ldet = 0.f;
#pragma unroll
        for (int i = 0; i < 6; ++i) ldet += logf(Lo[i][i]);
        ldet *= 2.f;
        const float hr[6] = {ef.h0, ef.h1, ef.h2, ef.h3, ef.h4, ef.h5};
        float yv[6];
#pragma unroll
        for (int i = 0; i < 6; ++i) {
            float sum = s[i] * hr[i];
#pragma unroll
            for (int m = 0; m < 6; ++m) if (m < i) sum -= Lo[i][m] * yv[m];
            yv[i] = sum / Lo[i][i];
        }
        float qd = 0.f;
#pragma unroll
        for (int i = 0; i < 6; ++i) qd += yv[i] * yv[i];
        double llc = (double)ef.g - 0.5 * (double)ldet + 0.5 * (double)qd;

        const float bgv[4] = {bsc0, bsc1, bsc0, bsc1};
        const double r = (double)rr;
        const double T_ = 4096.0;
#pragma unroll
        for (int gg = 0; gg < 4; ++gg) {
            const double bb = (double)bgv[gg];
            const double sumz = (double)csz[gg];
            const double sumz2 = (double)csz2[gg];
            const double Zp = sumz2 - sumz * sumz / 16.0;
            const double Sqp = (double)axv[gg] - (double)axv[4 + gg];
            llc += -0.5 * Sqp / r
                   + 0.5 * (bb / (r * (r + T_ * bb))) * Zp
                   - 7.5 * ((T_ - 1.0) * log(r) + log(r + T_ * bb))
                   - 7.5 * T_ * LOG2PI;
        }
        out[0] = (float)llc;
    }
}

extern "C" void kernel_launch(void* const* d_in, const int* in_sizes, int n_in,
                              void* d_out, int out_size, void* d_ws, size_t ws_size,
                              hipStream_t stream) {
    const float* track            = (const float*)d_in[0];
    const float* bias_scales      = (const float*)d_in[1];
    const float* obs_noise        = (const float*)d_in[2];
    const float* trans_noise      = (const float*)d_in[3];
    const float* transition_param = (const float*)d_in[4];
    float* ws = (float*)d_ws;
    float* out = (float*)d_out;

    fused_kernel<<<64, 256, 0, stream>>>(track, ws, bias_scales,
                                         obs_noise, trans_noise, transition_param, out);
}